// Round 3
// baseline (1240.701 us; speedup 1.0000x reference)
//
#include <hip/hip_runtime.h>
#include <cstdint>
#include <cstddef>

#define BN_EPS 1e-5f

// ---------------- helpers ----------------

__device__ __forceinline__ int edge_at(const void* e, long long i, int m64) {
  return m64 ? (int)((const long long*)e)[i] : ((const int*)e)[i];
}

__device__ __forceinline__ unsigned short f2bf(float f) {
  unsigned int u = __float_as_uint(f);
  unsigned int r = (u + 0x7FFFu + ((u >> 16) & 1u)) >> 16;
  return (unsigned short)r;
}

// Detect int64 vs int32 edge_index: indices are 0..n-1 < 2^31, so for int64
// data every odd 32-bit word is 0.
__global__ void detect_kernel(const int* __restrict__ e, int* __restrict__ mode) {
  int nz = 0;
  for (int i = 1; i < 512; i += 2) nz |= e[i];
  mode[0] = (nz == 0) ? 1 : 0;
}

// ---------------- bucketed CSR build ----------------
// bucket b = target nodes [b*256, (b+1)*256)

// per-block LDS histogram of bucket counts -> global bcount
__global__ __launch_bounds__(256) void bhist_kernel(const void* __restrict__ edges,
                                                    const int* __restrict__ mode,
                                                    int* __restrict__ bcount, int E, int nb) {
  __shared__ int h[1024];
  int m = mode[0];
  for (int i = threadIdx.x; i < nb; i += 256) h[i] = 0;
  __syncthreads();
  long long i = (long long)blockIdx.x * 256 + threadIdx.x;
  long long stride = (long long)gridDim.x * 256;
  for (; i < E; i += stride) {
    int c = edge_at(edges, (long long)E + i, m);
    atomicAdd(&h[c >> 8], 1);
  }
  __syncthreads();
  for (int i = threadIdx.x; i < nb; i += 256)
    if (h[i]) atomicAdd(&bcount[i], h[i]);
}

// single-block scan of bucket counts (nb <= 1024) -> boff (exclusive) + bcursor
__global__ __launch_bounds__(1024) void bscan_kernel(const int* __restrict__ bcount,
                                                     int* __restrict__ boff,
                                                     int* __restrict__ bcursor, int nb) {
  __shared__ int s[1024];
  int t = threadIdx.x;
  int v = (t < nb) ? bcount[t] : 0;
  s[t] = v;
  __syncthreads();
  for (int off = 1; off < 1024; off <<= 1) {
    int u = (t >= off) ? s[t - off] : 0;
    __syncthreads();
    s[t] += u;
    __syncthreads();
  }
  if (t < nb) {
    boff[t] = s[t] - v;
    bcursor[t] = s[t] - v;
  }
  if (t == 0) boff[nb] = s[1023];
}

// scatter packed (row<<8 | col&255) into bucket regions (391 write frontiers)
__global__ __launch_bounds__(256) void passA_kernel(const void* __restrict__ edges,
                                                    const int* __restrict__ mode,
                                                    int* __restrict__ bcursor,
                                                    int* __restrict__ pairs, int E) {
  int m = mode[0];
  long long i = (long long)blockIdx.x * 256 + threadIdx.x;
  long long stride = (long long)gridDim.x * 256;
  for (; i < E; i += stride) {
    int r = edge_at(edges, i, m);
    int c = edge_at(edges, (long long)E + i, m);
    int pos = atomicAdd(&bcursor[c >> 8], 1);
    pairs[pos] = (r << 8) | (c & 255);
  }
}

// per-bucket LDS histogram -> deg (coalesced writes, no global random atomics)
__global__ __launch_bounds__(256) void passB1_kernel(const int* __restrict__ pairs,
                                                     const int* __restrict__ boff,
                                                     int* __restrict__ deg, int n) {
  __shared__ int h[256];
  int b = blockIdx.x;
  h[threadIdx.x] = 0;
  __syncthreads();
  int lo = boff[b], hi = boff[b + 1];
  for (int e = lo + threadIdx.x; e < hi; e += 256)
    atomicAdd(&h[pairs[e] & 255], 1);
  __syncthreads();
  int node = b * 256 + threadIdx.x;
  if (node < n) deg[node] = h[threadIdx.x];
}

__global__ void dinv_kernel(const int* __restrict__ deg, float* __restrict__ dinv, int n) {
  int i = blockIdx.x * blockDim.x + threadIdx.x;
  if (i < n) dinv[i] = deg[i] > 0 ? rsqrtf((float)deg[i]) : 0.f;
}

// ---- hierarchical exclusive scan of deg -> offsets ----
__global__ __launch_bounds__(256) void scan1_kernel(const int* __restrict__ deg,
                                                    int* __restrict__ tprefix,
                                                    int* __restrict__ bsum, int n) {
  __shared__ int s[256];
  int t = threadIdx.x;
  int gid = blockIdx.x * 256 + t;
  int base = gid * 4;
  int sum = 0;
#pragma unroll
  for (int j = 0; j < 4; j++) {
    int i = base + j;
    if (i < n) sum += deg[i];
  }
  s[t] = sum;
  __syncthreads();
  for (int off = 1; off < 256; off <<= 1) {
    int v = (t >= off) ? s[t - off] : 0;
    __syncthreads();
    s[t] += v;
    __syncthreads();
  }
  tprefix[gid] = s[t] - sum;
  if (t == 255) bsum[blockIdx.x] = s[255];
}

__global__ __launch_bounds__(256) void scan2_kernel(int* __restrict__ bsum, int nbk,
                                                    int* __restrict__ offsets, int n) {
  __shared__ int s[256];
  int t = threadIdx.x;
  int v = (t < nbk) ? bsum[t] : 0;
  s[t] = v;
  __syncthreads();
  for (int off = 1; off < 256; off <<= 1) {
    int u = (t >= off) ? s[t - off] : 0;
    __syncthreads();
    s[t] += u;
    __syncthreads();
  }
  if (t < nbk) bsum[t] = s[t] - v;
  if (t == 255) offsets[n] = s[255];
}

__global__ __launch_bounds__(256) void scan3_kernel(const int* __restrict__ deg,
                                                    const int* __restrict__ tprefix,
                                                    const int* __restrict__ bsum,
                                                    int* __restrict__ offsets, int n) {
  int gid = blockIdx.x * 256 + threadIdx.x;
  int run = bsum[blockIdx.x] + tprefix[gid];
  int base = gid * 4;
#pragma unroll
  for (int j = 0; j < 4; j++) {
    int i = base + j;
    if (i < n) {
      offsets[i] = run;
      run += deg[i];
    }
  }
}

// per-bucket CSR fill: LDS cursors, writes land in the bucket's contiguous range
__global__ __launch_bounds__(256) void passB2_kernel(const int* __restrict__ pairs,
                                                     const int* __restrict__ boff,
                                                     const int* __restrict__ offsets,
                                                     int* __restrict__ csr_row, int n) {
  __shared__ int cur[256];
  int b = blockIdx.x;
  int node = b * 256 + threadIdx.x;
  cur[threadIdx.x] = (node < n) ? offsets[node] : 0;
  __syncthreads();
  int lo = boff[b], hi = boff[b + 1];
  for (int e = lo + threadIdx.x; e < hi; e += 256) {
    int p = pairs[e];
    int pos = atomicAdd(&cur[p & 255], 1);
    csr_row[pos] = p >> 8;
  }
}

// ---------------- per-layer kernels ----------------

// xb[i][:] = bf16( dinv[i] * ( affine(in[i][:]) @ W ) )
__global__ __launch_bounds__(256) void gemm_kernel(
    const float* __restrict__ in, const float* __restrict__ W,
    const float* __restrict__ scale, const float* __restrict__ shift, int use_affine,
    const float* __restrict__ dinv, unsigned short* __restrict__ xb, int n) {
  __shared__ float A[64][33];
  __shared__ float Bs[32][128];
  int tid = threadIdx.x;
  int row0 = blockIdx.x * 64;
  int tc = tid & 15;
  int tr = tid >> 4;
  float acc[4][8] = {};

  for (int kt = 0; kt < 128; kt += 32) {
    {
      int r = tid >> 2;
      int c = (tid & 3) * 8;
      int grow = row0 + r;
      if (grow < n) {
        const float* src = in + (size_t)grow * 128 + kt + c;
        float4 v0 = *(const float4*)(src);
        float4 v1 = *(const float4*)(src + 4);
        float vv[8] = {v0.x, v0.y, v0.z, v0.w, v1.x, v1.y, v1.z, v1.w};
        if (use_affine) {
#pragma unroll
          for (int j = 0; j < 8; j++) vv[j] = vv[j] * scale[kt + c + j] + shift[kt + c + j];
        }
#pragma unroll
        for (int j = 0; j < 8; j++) A[r][c + j] = vv[j];
      } else {
#pragma unroll
        for (int j = 0; j < 8; j++) A[r][c + j] = 0.f;
      }
    }
    {
      int kr = tid >> 3;
      int c = (tid & 7) * 16;
      const float* src = W + (size_t)(kt + kr) * 128 + c;
      float4* dst = (float4*)&Bs[kr][c];
      dst[0] = ((const float4*)src)[0];
      dst[1] = ((const float4*)src)[1];
      dst[2] = ((const float4*)src)[2];
      dst[3] = ((const float4*)src)[3];
    }
    __syncthreads();
#pragma unroll
    for (int k = 0; k < 32; k++) {
      float av[4];
#pragma unroll
      for (int i = 0; i < 4; i++) av[i] = A[tr * 4 + i][k];
      float4 b0 = *(const float4*)&Bs[k][tc * 8];
      float4 b1 = *(const float4*)&Bs[k][tc * 8 + 4];
      float bv[8] = {b0.x, b0.y, b0.z, b0.w, b1.x, b1.y, b1.z, b1.w};
#pragma unroll
      for (int i = 0; i < 4; i++)
#pragma unroll
        for (int j = 0; j < 8; j++) acc[i][j] += av[i] * bv[j];
    }
    __syncthreads();
  }

#pragma unroll
  for (int i = 0; i < 4; i++) {
    int grow = row0 + tr * 4 + i;
    if (grow < n) {
      float dv = dinv[grow];
      unsigned int w0 = f2bf(acc[i][0] * dv) | ((unsigned int)f2bf(acc[i][1] * dv) << 16);
      unsigned int w1 = f2bf(acc[i][2] * dv) | ((unsigned int)f2bf(acc[i][3] * dv) << 16);
      unsigned int w2 = f2bf(acc[i][4] * dv) | ((unsigned int)f2bf(acc[i][5] * dv) << 16);
      unsigned int w3 = f2bf(acc[i][6] * dv) | ((unsigned int)f2bf(acc[i][7] * dv) << 16);
      uint4 o = make_uint4(w0, w1, w2, w3);
      *(uint4*)(xb + (size_t)grow * 128 + tc * 8) = o;
    }
  }
}

// z[c][:] = dinv[c] * sum over incoming edges of xb[row][:]  (bf16 gather, fp32 accum)
__global__ __launch_bounds__(256) void agg_kernel(
    const uint2* __restrict__ x2, const int* __restrict__ csr_row,
    const int* __restrict__ offsets, const float* __restrict__ dinv,
    float4* __restrict__ z4, int n) {
  int node = blockIdx.x * 8 + (threadIdx.x >> 5);
  int d4 = threadIdx.x & 31;  // 4 bf16 per lane
  if (node >= n) return;
  int lo = offsets[node], hi = offsets[node + 1];
  float4 a0 = {0, 0, 0, 0}, a1 = {0, 0, 0, 0}, a2 = {0, 0, 0, 0}, a3 = {0, 0, 0, 0};
  int e = lo;
  for (; e + 4 <= hi; e += 4) {
    int r0 = csr_row[e];
    int r1 = csr_row[e + 1];
    int r2 = csr_row[e + 2];
    int r3 = csr_row[e + 3];
    uint2 v0 = x2[(size_t)r0 * 32 + d4];
    uint2 v1 = x2[(size_t)r1 * 32 + d4];
    uint2 v2 = x2[(size_t)r2 * 32 + d4];
    uint2 v3 = x2[(size_t)r3 * 32 + d4];
    a0.x += __uint_as_float(v0.x << 16); a0.y += __uint_as_float(v0.x & 0xffff0000u);
    a0.z += __uint_as_float(v0.y << 16); a0.w += __uint_as_float(v0.y & 0xffff0000u);
    a1.x += __uint_as_float(v1.x << 16); a1.y += __uint_as_float(v1.x & 0xffff0000u);
    a1.z += __uint_as_float(v1.y << 16); a1.w += __uint_as_float(v1.y & 0xffff0000u);
    a2.x += __uint_as_float(v2.x << 16); a2.y += __uint_as_float(v2.x & 0xffff0000u);
    a2.z += __uint_as_float(v2.y << 16); a2.w += __uint_as_float(v2.y & 0xffff0000u);
    a3.x += __uint_as_float(v3.x << 16); a3.y += __uint_as_float(v3.x & 0xffff0000u);
    a3.z += __uint_as_float(v3.y << 16); a3.w += __uint_as_float(v3.y & 0xffff0000u);
  }
  for (; e < hi; e++) {
    int r = csr_row[e];
    uint2 v = x2[(size_t)r * 32 + d4];
    a0.x += __uint_as_float(v.x << 16); a0.y += __uint_as_float(v.x & 0xffff0000u);
    a0.z += __uint_as_float(v.y << 16); a0.w += __uint_as_float(v.y & 0xffff0000u);
  }
  float dv = dinv[node];
  float4 s;
  s.x = (a0.x + a1.x + a2.x + a3.x) * dv;
  s.y = (a0.y + a1.y + a2.y + a3.y) * dv;
  s.z = (a0.z + a1.z + a2.z + a3.z) * dv;
  s.w = (a0.w + a1.w + a2.w + a3.w) * dv;
  z4[(size_t)node * 32 + d4] = s;
}

__global__ __launch_bounds__(128) void stats_kernel(
    const float* __restrict__ z, float* __restrict__ colsum,
    float* __restrict__ colsumsq, int n) {
  int d = threadIdx.x;
  float s = 0.f, s2 = 0.f;
  for (int r = blockIdx.x; r < n; r += gridDim.x) {
    float v = z[(size_t)r * 128 + d];
    s += v;
    s2 += v * v;
  }
  atomicAdd(&colsum[d], s);
  atomicAdd(&colsumsq[d], s2);
}

__global__ void finalize_kernel(const float* __restrict__ colsum,
                                const float* __restrict__ colsumsq,
                                const float* __restrict__ gamma,
                                const float* __restrict__ beta,
                                float* __restrict__ scale, float* __restrict__ shift,
                                float invN) {
  int d = threadIdx.x;
  float mu = colsum[d] * invN;
  float var = colsumsq[d] * invN - mu * mu;
  var = fmaxf(var, 0.f);
  float sc = gamma[d] * rsqrtf(var + BN_EPS);
  scale[d] = sc;
  shift[d] = beta[d] - mu * sc;
}

__global__ __launch_bounds__(256) void norm_kernel(
    const float* __restrict__ z, const float* __restrict__ scale,
    const float* __restrict__ shift, float* __restrict__ out, int total4) {
  int idx = blockIdx.x * blockDim.x + threadIdx.x;
  int stride = gridDim.x * blockDim.x;
  for (int i = idx; i < total4; i += stride) {
    float4 v = ((const float4*)z)[i];
    int d0 = (i & 31) * 4;
    v.x = v.x * scale[d0] + shift[d0];
    v.y = v.y * scale[d0 + 1] + shift[d0 + 1];
    v.z = v.z * scale[d0 + 2] + shift[d0 + 2];
    v.w = v.w * scale[d0 + 3] + shift[d0 + 3];
    ((float4*)out)[i] = v;
  }
}

// ---------------- launcher ----------------

extern "C" void kernel_launch(void* const* d_in, const int* in_sizes, int n_in,
                              void* d_out, int out_size, void* d_ws, size_t ws_size,
                              hipStream_t stream) {
  const float* feats = (const float*)d_in[0];
  const void* edges = d_in[1];
  const float* W = (const float*)d_in[2];
  const float* gamma = (const float*)d_in[4];
  const float* beta = (const float*)d_in[5];

  const int n = in_sizes[0] / 128;
  const int E = in_sizes[1] / 2;

  const int nb = (n + 255) / 256;           // CSR buckets (<=1024)
  const int scan_blocks = (n + 1023) / 1024;  // node scan (<=256 blocks)

  char* ws = (char*)d_ws;
  size_t off = 0;
  unsigned short* xb = (unsigned short*)(ws + off); off += (size_t)n * 128 * 2; off = (off + 255) & ~(size_t)255;
  int* deg = (int*)(ws + off); off += (size_t)n * 4;
  float* dinv = (float*)(ws + off); off += (size_t)n * 4;
  int* offsets = (int*)(ws + off); off += (size_t)(n + 1) * 4; off = (off + 255) & ~(size_t)255;
  int* csr_row = (int*)(ws + off); off += (size_t)E * 4; off = (off + 255) & ~(size_t)255;
  int* pairs = (int*)(ws + off); off += (size_t)E * 4; off = (off + 255) & ~(size_t)255;
  int* tprefix = (int*)(ws + off); off += (size_t)scan_blocks * 256 * 4; off = (off + 255) & ~(size_t)255;
  int* bsum = (int*)(ws + off); off += 256 * 4;
  int* bcount = (int*)(ws + off); off += 1024 * 4;
  int* boff = (int*)(ws + off); off += 1025 * 4;
  int* bcursor = (int*)(ws + off); off += 1024 * 4;
  float* colsum = (float*)(ws + off); off += 128 * 4;
  float* colsumsq = (float*)(ws + off); off += 128 * 4;
  float* scale = (float*)(ws + off); off += 128 * 4;
  float* shift = (float*)(ws + off); off += 128 * 4;
  int* mode = (int*)(ws + off); off += 4;

  // ---- bucketed CSR build (graph is layer-invariant) ----
  hipMemsetAsync(bcount, 0, (size_t)nb * 4, stream);
  detect_kernel<<<1, 1, 0, stream>>>((const int*)edges, mode);
  bhist_kernel<<<256, 256, 0, stream>>>(edges, mode, bcount, E, nb);
  bscan_kernel<<<1, 1024, 0, stream>>>(bcount, boff, bcursor, nb);
  passA_kernel<<<1024, 256, 0, stream>>>(edges, mode, bcursor, pairs, E);
  passB1_kernel<<<nb, 256, 0, stream>>>(pairs, boff, deg, n);
  dinv_kernel<<<(n + 255) / 256, 256, 0, stream>>>(deg, dinv, n);
  scan1_kernel<<<scan_blocks, 256, 0, stream>>>(deg, tprefix, bsum, n);
  scan2_kernel<<<1, 256, 0, stream>>>(bsum, scan_blocks, offsets, n);
  scan3_kernel<<<scan_blocks, 256, 0, stream>>>(deg, tprefix, bsum, offsets, n);
  passB2_kernel<<<nb, 256, 0, stream>>>(pairs, boff, offsets, csr_row, n);

  float* z = (float*)d_out;
  for (int l = 0; l < 3; l++) {
    const float* in = (l == 0) ? feats : z;
    gemm_kernel<<<(n + 63) / 64, 256, 0, stream>>>(
        in, W + (size_t)l * 128 * 128, scale, shift, l > 0 ? 1 : 0, dinv, xb, n);
    hipMemsetAsync(colsum, 0, 2 * 128 * 4, stream);
    agg_kernel<<<(n + 7) / 8, 256, 0, stream>>>(
        (const uint2*)xb, csr_row, offsets, dinv, (float4*)z, n);
    stats_kernel<<<512, 128, 0, stream>>>(z, colsum, colsumsq, n);
    finalize_kernel<<<1, 128, 0, stream>>>(colsum, colsumsq, gamma + l * 128,
                                           beta + l * 128, scale, shift, 1.0f / (float)n);
  }
  norm_kernel<<<2048, 256, 0, stream>>>(z, scale, shift, (float*)d_out, (n * 128) / 4);
}

// Round 4
// 662.168 us; speedup vs baseline: 1.8737x; 1.8737x over previous
//
#include <hip/hip_runtime.h>
#include <cstdint>
#include <cstddef>

#define BN_EPS 1e-5f
#define NCHUNK 256  // blocks in the edge-chunk partition (counting sort)

// ---------------- helpers ----------------

__device__ __forceinline__ int edge_at(const void* e, long long i, int m64) {
  return m64 ? (int)((const long long*)e)[i] : ((const int*)e)[i];
}

__device__ __forceinline__ unsigned short f2bf(float f) {
  unsigned int u = __float_as_uint(f);
  unsigned int r = (u + 0x7FFFu + ((u >> 16) & 1u)) >> 16;
  return (unsigned short)r;
}

// Detect int64 vs int32 edge_index: indices are 0..n-1 < 2^31, so for int64
// data every odd 32-bit word is 0.
__global__ void detect_kernel(const int* __restrict__ e, int* __restrict__ mode) {
  int nz = 0;
  for (int i = 1; i < 512; i += 2) nz |= e[i];
  mode[0] = (nz == 0) ? 1 : 0;
}

// ---------------- contention-free counting sort by bucket ----------------
// bucket b = target nodes [b*256, (b+1)*256); block k owns edge chunk k.
// blockcounts layout: [bucket][block]  (bucket-major -> direct scan gives slots)

__global__ __launch_bounds__(256) void count_kernel(const void* __restrict__ edges,
                                                    const int* __restrict__ mode,
                                                    int* __restrict__ blockcounts,
                                                    int E, int nb, int chunk) {
  __shared__ int h[1024];
  int m = mode[0];
  for (int i = threadIdx.x; i < nb; i += 256) h[i] = 0;
  __syncthreads();
  long long lo = (long long)blockIdx.x * chunk;
  long long hi = lo + chunk;
  if (hi > E) hi = E;
  for (long long i = lo + threadIdx.x; i < hi; i += 256) {
    int c = edge_at(edges, (long long)E + i, m);
    atomicAdd(&h[c >> 8], 1);
  }
  __syncthreads();
  for (int j = threadIdx.x; j < nb; j += 256)
    blockcounts[(size_t)j * NCHUNK + blockIdx.x] = h[j];
}

// ---- generic hierarchical exclusive scan (4 elems/thread) ----
__global__ __launch_bounds__(256) void scan1_kernel(const int* __restrict__ src,
                                                    int* __restrict__ tprefix,
                                                    int* __restrict__ bsum, int n) {
  __shared__ int s[256];
  int t = threadIdx.x;
  int gid = blockIdx.x * 256 + t;
  int base = gid * 4;
  int sum = 0;
#pragma unroll
  for (int j = 0; j < 4; j++) {
    int i = base + j;
    if (i < n) sum += src[i];
  }
  s[t] = sum;
  __syncthreads();
  for (int off = 1; off < 256; off <<= 1) {
    int v = (t >= off) ? s[t - off] : 0;
    __syncthreads();
    s[t] += v;
    __syncthreads();
  }
  tprefix[gid] = s[t] - sum;
  if (t == 255) bsum[blockIdx.x] = s[255];
}

__global__ __launch_bounds__(256) void scan2_kernel(int* __restrict__ bsum, int nbk,
                                                    int* __restrict__ out, int n) {
  __shared__ int s[256];
  int t = threadIdx.x;
  int v = (t < nbk) ? bsum[t] : 0;
  s[t] = v;
  __syncthreads();
  for (int off = 1; off < 256; off <<= 1) {
    int u = (t >= off) ? s[t - off] : 0;
    __syncthreads();
    s[t] += u;
    __syncthreads();
  }
  if (t < nbk) bsum[t] = s[t] - v;
  if (t == 255) out[n] = s[255];
}

__global__ __launch_bounds__(256) void scan3_kernel(const int* __restrict__ src,
                                                    const int* __restrict__ tprefix,
                                                    const int* __restrict__ bsum,
                                                    int* __restrict__ out, int n) {
  int gid = blockIdx.x * 256 + threadIdx.x;
  int run = bsum[blockIdx.x] + tprefix[gid];
  int base = gid * 4;
#pragma unroll
  for (int j = 0; j < 4; j++) {
    int i = base + j;
    if (i < n) {
      int c = src[i];
      out[i] = run;
      run += c;
    }
  }
}

// scatter edges into bucket-sorted `pairs` using LDS cursors (no global atomics)
__global__ __launch_bounds__(256) void scatter_kernel(const void* __restrict__ edges,
                                                      const int* __restrict__ mode,
                                                      const int* __restrict__ moff,
                                                      int* __restrict__ pairs,
                                                      int E, int nb, int chunk) {
  __shared__ int cur[1024];
  int m = mode[0];
  for (int j = threadIdx.x; j < nb; j += 256)
    cur[j] = moff[(size_t)j * NCHUNK + blockIdx.x];
  __syncthreads();
  long long lo = (long long)blockIdx.x * chunk;
  long long hi = lo + chunk;
  if (hi > E) hi = E;
  for (long long i = lo + threadIdx.x; i < hi; i += 256) {
    int r = edge_at(edges, i, m);
    int c = edge_at(edges, (long long)E + i, m);
    int pos = atomicAdd(&cur[c >> 8], 1);
    pairs[pos] = (r << 8) | (c & 255);
  }
}

// per-bucket LDS histogram -> deg (coalesced writes, no global random atomics)
__global__ __launch_bounds__(256) void passB1_kernel(const int* __restrict__ pairs,
                                                     const int* __restrict__ moff,
                                                     int* __restrict__ deg, int n) {
  __shared__ int h[256];
  int b = blockIdx.x;
  h[threadIdx.x] = 0;
  __syncthreads();
  int lo = moff[(size_t)b * NCHUNK];
  int hi = moff[(size_t)(b + 1) * NCHUNK];
  for (int e = lo + threadIdx.x; e < hi; e += 256)
    atomicAdd(&h[pairs[e] & 255], 1);
  __syncthreads();
  int node = b * 256 + threadIdx.x;
  if (node < n) deg[node] = h[threadIdx.x];
}

__global__ void dinv_kernel(const int* __restrict__ deg, float* __restrict__ dinv, int n) {
  int i = blockIdx.x * blockDim.x + threadIdx.x;
  if (i < n) dinv[i] = deg[i] > 0 ? rsqrtf((float)deg[i]) : 0.f;
}

// per-bucket CSR fill: LDS cursors, writes land in the bucket's contiguous range
__global__ __launch_bounds__(256) void passB2_kernel(const int* __restrict__ pairs,
                                                     const int* __restrict__ moff,
                                                     const int* __restrict__ offsets,
                                                     int* __restrict__ csr_row, int n) {
  __shared__ int cur[256];
  int b = blockIdx.x;
  int node = b * 256 + threadIdx.x;
  cur[threadIdx.x] = (node < n) ? offsets[node] : 0;
  __syncthreads();
  int lo = moff[(size_t)b * NCHUNK];
  int hi = moff[(size_t)(b + 1) * NCHUNK];
  for (int e = lo + threadIdx.x; e < hi; e += 256) {
    int p = pairs[e];
    int pos = atomicAdd(&cur[p & 255], 1);
    csr_row[pos] = p >> 8;
  }
}

// ---------------- per-layer kernels ----------------

// xb[i][:] = bf16( dinv[i] * ( affine(in[i][:]) @ W ) )
__global__ __launch_bounds__(256) void gemm_kernel(
    const float* __restrict__ in, const float* __restrict__ W,
    const float* __restrict__ scale, const float* __restrict__ shift, int use_affine,
    const float* __restrict__ dinv, unsigned short* __restrict__ xb, int n) {
  __shared__ float A[64][33];
  __shared__ float Bs[32][128];
  int tid = threadIdx.x;
  int row0 = blockIdx.x * 64;
  int tc = tid & 15;
  int tr = tid >> 4;
  float acc[4][8] = {};

  for (int kt = 0; kt < 128; kt += 32) {
    {
      int r = tid >> 2;
      int c = (tid & 3) * 8;
      int grow = row0 + r;
      if (grow < n) {
        const float* src = in + (size_t)grow * 128 + kt + c;
        float4 v0 = *(const float4*)(src);
        float4 v1 = *(const float4*)(src + 4);
        float vv[8] = {v0.x, v0.y, v0.z, v0.w, v1.x, v1.y, v1.z, v1.w};
        if (use_affine) {
#pragma unroll
          for (int j = 0; j < 8; j++) vv[j] = vv[j] * scale[kt + c + j] + shift[kt + c + j];
        }
#pragma unroll
        for (int j = 0; j < 8; j++) A[r][c + j] = vv[j];
      } else {
#pragma unroll
        for (int j = 0; j < 8; j++) A[r][c + j] = 0.f;
      }
    }
    {
      int kr = tid >> 3;
      int c = (tid & 7) * 16;
      const float* src = W + (size_t)(kt + kr) * 128 + c;
      float4* dst = (float4*)&Bs[kr][c];
      dst[0] = ((const float4*)src)[0];
      dst[1] = ((const float4*)src)[1];
      dst[2] = ((const float4*)src)[2];
      dst[3] = ((const float4*)src)[3];
    }
    __syncthreads();
#pragma unroll
    for (int k = 0; k < 32; k++) {
      float av[4];
#pragma unroll
      for (int i = 0; i < 4; i++) av[i] = A[tr * 4 + i][k];
      float4 b0 = *(const float4*)&Bs[k][tc * 8];
      float4 b1 = *(const float4*)&Bs[k][tc * 8 + 4];
      float bv[8] = {b0.x, b0.y, b0.z, b0.w, b1.x, b1.y, b1.z, b1.w};
#pragma unroll
      for (int i = 0; i < 4; i++)
#pragma unroll
        for (int j = 0; j < 8; j++) acc[i][j] += av[i] * bv[j];
    }
    __syncthreads();
  }

#pragma unroll
  for (int i = 0; i < 4; i++) {
    int grow = row0 + tr * 4 + i;
    if (grow < n) {
      float dv = dinv[grow];
      unsigned int w0 = f2bf(acc[i][0] * dv) | ((unsigned int)f2bf(acc[i][1] * dv) << 16);
      unsigned int w1 = f2bf(acc[i][2] * dv) | ((unsigned int)f2bf(acc[i][3] * dv) << 16);
      unsigned int w2 = f2bf(acc[i][4] * dv) | ((unsigned int)f2bf(acc[i][5] * dv) << 16);
      unsigned int w3 = f2bf(acc[i][6] * dv) | ((unsigned int)f2bf(acc[i][7] * dv) << 16);
      uint4 o = make_uint4(w0, w1, w2, w3);
      *(uint4*)(xb + (size_t)grow * 128 + tc * 8) = o;
    }
  }
}

// z[c][:] = dinv[c] * sum over incoming edges of xb[row][:]  (bf16 gather, fp32 accum)
__global__ __launch_bounds__(256) void agg_kernel(
    const uint2* __restrict__ x2, const int* __restrict__ csr_row,
    const int* __restrict__ offsets, const float* __restrict__ dinv,
    float4* __restrict__ z4, int n) {
  int node = blockIdx.x * 8 + (threadIdx.x >> 5);
  int d4 = threadIdx.x & 31;  // 4 bf16 per lane
  if (node >= n) return;
  int lo = offsets[node], hi = offsets[node + 1];
  float4 a0 = {0, 0, 0, 0}, a1 = {0, 0, 0, 0}, a2 = {0, 0, 0, 0}, a3 = {0, 0, 0, 0};
  int e = lo;
  for (; e + 4 <= hi; e += 4) {
    int r0 = csr_row[e];
    int r1 = csr_row[e + 1];
    int r2 = csr_row[e + 2];
    int r3 = csr_row[e + 3];
    uint2 v0 = x2[(size_t)r0 * 32 + d4];
    uint2 v1 = x2[(size_t)r1 * 32 + d4];
    uint2 v2 = x2[(size_t)r2 * 32 + d4];
    uint2 v3 = x2[(size_t)r3 * 32 + d4];
    a0.x += __uint_as_float(v0.x << 16); a0.y += __uint_as_float(v0.x & 0xffff0000u);
    a0.z += __uint_as_float(v0.y << 16); a0.w += __uint_as_float(v0.y & 0xffff0000u);
    a1.x += __uint_as_float(v1.x << 16); a1.y += __uint_as_float(v1.x & 0xffff0000u);
    a1.z += __uint_as_float(v1.y << 16); a1.w += __uint_as_float(v1.y & 0xffff0000u);
    a2.x += __uint_as_float(v2.x << 16); a2.y += __uint_as_float(v2.x & 0xffff0000u);
    a2.z += __uint_as_float(v2.y << 16); a2.w += __uint_as_float(v2.y & 0xffff0000u);
    a3.x += __uint_as_float(v3.x << 16); a3.y += __uint_as_float(v3.x & 0xffff0000u);
    a3.z += __uint_as_float(v3.y << 16); a3.w += __uint_as_float(v3.y & 0xffff0000u);
  }
  for (; e < hi; e++) {
    int r = csr_row[e];
    uint2 v = x2[(size_t)r * 32 + d4];
    a0.x += __uint_as_float(v.x << 16); a0.y += __uint_as_float(v.x & 0xffff0000u);
    a0.z += __uint_as_float(v.y << 16); a0.w += __uint_as_float(v.y & 0xffff0000u);
  }
  float dv = dinv[node];
  float4 s;
  s.x = (a0.x + a1.x + a2.x + a3.x) * dv;
  s.y = (a0.y + a1.y + a2.y + a3.y) * dv;
  s.z = (a0.z + a1.z + a2.z + a3.z) * dv;
  s.w = (a0.w + a1.w + a2.w + a3.w) * dv;
  z4[(size_t)node * 32 + d4] = s;
}

__global__ __launch_bounds__(128) void stats_kernel(
    const float* __restrict__ z, float* __restrict__ colsum,
    float* __restrict__ colsumsq, int n) {
  int d = threadIdx.x;
  float s = 0.f, s2 = 0.f;
  for (int r = blockIdx.x; r < n; r += gridDim.x) {
    float v = z[(size_t)r * 128 + d];
    s += v;
    s2 += v * v;
  }
  atomicAdd(&colsum[d], s);
  atomicAdd(&colsumsq[d], s2);
}

__global__ void finalize_kernel(const float* __restrict__ colsum,
                                const float* __restrict__ colsumsq,
                                const float* __restrict__ gamma,
                                const float* __restrict__ beta,
                                float* __restrict__ scale, float* __restrict__ shift,
                                float invN) {
  int d = threadIdx.x;
  float mu = colsum[d] * invN;
  float var = colsumsq[d] * invN - mu * mu;
  var = fmaxf(var, 0.f);
  float sc = gamma[d] * rsqrtf(var + BN_EPS);
  scale[d] = sc;
  shift[d] = beta[d] - mu * sc;
}

__global__ __launch_bounds__(256) void norm_kernel(
    const float* __restrict__ z, const float* __restrict__ scale,
    const float* __restrict__ shift, float* __restrict__ out, int total4) {
  int idx = blockIdx.x * blockDim.x + threadIdx.x;
  int stride = gridDim.x * blockDim.x;
  for (int i = idx; i < total4; i += stride) {
    float4 v = ((const float4*)z)[i];
    int d0 = (i & 31) * 4;
    v.x = v.x * scale[d0] + shift[d0];
    v.y = v.y * scale[d0 + 1] + shift[d0 + 1];
    v.z = v.z * scale[d0 + 2] + shift[d0 + 2];
    v.w = v.w * scale[d0 + 3] + shift[d0 + 3];
    ((float4*)out)[i] = v;
  }
}

// ---------------- launcher ----------------

extern "C" void kernel_launch(void* const* d_in, const int* in_sizes, int n_in,
                              void* d_out, int out_size, void* d_ws, size_t ws_size,
                              hipStream_t stream) {
  const float* feats = (const float*)d_in[0];
  const void* edges = d_in[1];
  const float* W = (const float*)d_in[2];
  const float* gamma = (const float*)d_in[4];
  const float* beta = (const float*)d_in[5];

  const int n = in_sizes[0] / 128;
  const int E = in_sizes[1] / 2;

  const int nb = (n + 255) / 256;              // buckets (<=1024)
  const int m = nb * NCHUNK;                   // count-matrix size
  const int chunk = (E + NCHUNK - 1) / NCHUNK; // edges per counting block
  const int sb_n = (n + 1023) / 1024;          // scan blocks (nodes)
  const int sb_m = (m + 1023) / 1024;          // scan blocks (matrix)
  const int sb_max = sb_n > sb_m ? sb_n : sb_m;

  char* ws = (char*)d_ws;
  size_t off = 0;
  unsigned short* xb = (unsigned short*)(ws + off); off += (size_t)n * 128 * 2; off = (off + 255) & ~(size_t)255;
  int* deg = (int*)(ws + off); off += (size_t)n * 4;
  float* dinv = (float*)(ws + off); off += (size_t)n * 4;
  int* offsets = (int*)(ws + off); off += (size_t)(n + 1) * 4; off = (off + 255) & ~(size_t)255;
  int* csr_row = (int*)(ws + off); off += (size_t)E * 4; off = (off + 255) & ~(size_t)255;
  int* pairs = (int*)(ws + off); off += (size_t)E * 4; off = (off + 255) & ~(size_t)255;
  int* blockcounts = (int*)(ws + off); off += (size_t)m * 4; off = (off + 255) & ~(size_t)255;
  int* moff = (int*)(ws + off); off += (size_t)(m + 1) * 4; off = (off + 255) & ~(size_t)255;
  int* tprefix = (int*)(ws + off); off += (size_t)sb_max * 256 * 4; off = (off + 255) & ~(size_t)255;
  int* bsum = (int*)(ws + off); off += 256 * 4;
  float* colsum = (float*)(ws + off); off += 128 * 4;
  float* colsumsq = (float*)(ws + off); off += 128 * 4;
  float* scale = (float*)(ws + off); off += 128 * 4;
  float* shift = (float*)(ws + off); off += 128 * 4;
  int* mode = (int*)(ws + off); off += 4;

  // ---- contention-free CSR build (graph is layer-invariant) ----
  detect_kernel<<<1, 1, 0, stream>>>((const int*)edges, mode);
  count_kernel<<<NCHUNK, 256, 0, stream>>>(edges, mode, blockcounts, E, nb, chunk);
  scan1_kernel<<<sb_m, 256, 0, stream>>>(blockcounts, tprefix, bsum, m);
  scan2_kernel<<<1, 256, 0, stream>>>(bsum, sb_m, moff, m);
  scan3_kernel<<<sb_m, 256, 0, stream>>>(blockcounts, tprefix, bsum, moff, m);
  scatter_kernel<<<NCHUNK, 256, 0, stream>>>(edges, mode, moff, pairs, E, nb, chunk);
  passB1_kernel<<<nb, 256, 0, stream>>>(pairs, moff, deg, n);
  dinv_kernel<<<(n + 255) / 256, 256, 0, stream>>>(deg, dinv, n);
  scan1_kernel<<<sb_n, 256, 0, stream>>>(deg, tprefix, bsum, n);
  scan2_kernel<<<1, 256, 0, stream>>>(bsum, sb_n, offsets, n);
  scan3_kernel<<<sb_n, 256, 0, stream>>>(deg, tprefix, bsum, offsets, n);
  passB2_kernel<<<nb, 256, 0, stream>>>(pairs, moff, offsets, csr_row, n);

  float* z = (float*)d_out;
  for (int l = 0; l < 3; l++) {
    const float* in = (l == 0) ? feats : z;
    gemm_kernel<<<(n + 63) / 64, 256, 0, stream>>>(
        in, W + (size_t)l * 128 * 128, scale, shift, l > 0 ? 1 : 0, dinv, xb, n);
    hipMemsetAsync(colsum, 0, 2 * 128 * 4, stream);
    agg_kernel<<<(n + 7) / 8, 256, 0, stream>>>(
        (const uint2*)xb, csr_row, offsets, dinv, (float4*)z, n);
    stats_kernel<<<512, 128, 0, stream>>>(z, colsum, colsumsq, n);
    finalize_kernel<<<1, 128, 0, stream>>>(colsum, colsumsq, gamma + l * 128,
                                           beta + l * 128, scale, shift, 1.0f / (float)n);
  }
  norm_kernel<<<2048, 256, 0, stream>>>(z, scale, shift, (float*)d_out, (n * 128) / 4);
}

// Round 5
// 590.073 us; speedup vs baseline: 2.1026x; 1.1222x over previous
//
#include <hip/hip_runtime.h>
#include <cstdint>
#include <cstddef>

#define BN_EPS 1e-5f
#define NCHUNK 256  // blocks in the edge-chunk partition (counting sort)

typedef short bf16x8 __attribute__((ext_vector_type(8)));
typedef float f32x4 __attribute__((ext_vector_type(4)));

// ---------------- helpers ----------------

__device__ __forceinline__ int edge_at(const void* e, long long i, int m64) {
  return m64 ? (int)((const long long*)e)[i] : ((const int*)e)[i];
}

__device__ __forceinline__ unsigned short f2bf(float f) {
  unsigned int u = __float_as_uint(f);
  unsigned int r = (u + 0x7FFFu + ((u >> 16) & 1u)) >> 16;
  return (unsigned short)r;
}

__device__ __forceinline__ unsigned int pack2bf(float lo, float hi) {
  return (unsigned int)f2bf(lo) | ((unsigned int)f2bf(hi) << 16);
}

// Detect int64 vs int32 edge_index
__global__ void detect_kernel(const int* __restrict__ e, int* __restrict__ mode) {
  int nz = 0;
  for (int i = 1; i < 512; i += 2) nz |= e[i];
  mode[0] = (nz == 0) ? 1 : 0;
}

// ---------------- contention-free counting sort by bucket ----------------

__global__ __launch_bounds__(256) void count_kernel(const void* __restrict__ edges,
                                                    const int* __restrict__ mode,
                                                    int* __restrict__ blockcounts,
                                                    int E, int nb, int chunk) {
  __shared__ int h[1024];
  int m = mode[0];
  for (int i = threadIdx.x; i < nb; i += 256) h[i] = 0;
  __syncthreads();
  long long lo = (long long)blockIdx.x * chunk;
  long long hi = lo + chunk;
  if (hi > E) hi = E;
  for (long long i = lo + threadIdx.x; i < hi; i += 256) {
    int c = edge_at(edges, (long long)E + i, m);
    atomicAdd(&h[c >> 8], 1);
  }
  __syncthreads();
  for (int j = threadIdx.x; j < nb; j += 256)
    blockcounts[(size_t)j * NCHUNK + blockIdx.x] = h[j];
}

// ---- generic hierarchical exclusive scan (4 elems/thread) ----
__global__ __launch_bounds__(256) void scan1_kernel(const int* __restrict__ src,
                                                    int* __restrict__ tprefix,
                                                    int* __restrict__ bsum, int n) {
  __shared__ int s[256];
  int t = threadIdx.x;
  int gid = blockIdx.x * 256 + t;
  int base = gid * 4;
  int sum = 0;
#pragma unroll
  for (int j = 0; j < 4; j++) {
    int i = base + j;
    if (i < n) sum += src[i];
  }
  s[t] = sum;
  __syncthreads();
  for (int off = 1; off < 256; off <<= 1) {
    int v = (t >= off) ? s[t - off] : 0;
    __syncthreads();
    s[t] += v;
    __syncthreads();
  }
  tprefix[gid] = s[t] - sum;
  if (t == 255) bsum[blockIdx.x] = s[255];
}

__global__ __launch_bounds__(256) void scan2_kernel(int* __restrict__ bsum, int nbk,
                                                    int* __restrict__ out, int n) {
  __shared__ int s[256];
  int t = threadIdx.x;
  int v = (t < nbk) ? bsum[t] : 0;
  s[t] = v;
  __syncthreads();
  for (int off = 1; off < 256; off <<= 1) {
    int u = (t >= off) ? s[t - off] : 0;
    __syncthreads();
    s[t] += u;
    __syncthreads();
  }
  if (t < nbk) bsum[t] = s[t] - v;
  if (t == 255) out[n] = s[255];
}

__global__ __launch_bounds__(256) void scan3_kernel(const int* __restrict__ src,
                                                    const int* __restrict__ tprefix,
                                                    const int* __restrict__ bsum,
                                                    int* __restrict__ out, int n) {
  int gid = blockIdx.x * 256 + threadIdx.x;
  int run = bsum[blockIdx.x] + tprefix[gid];
  int base = gid * 4;
#pragma unroll
  for (int j = 0; j < 4; j++) {
    int i = base + j;
    if (i < n) {
      int c = src[i];
      out[i] = run;
      run += c;
    }
  }
}

__global__ __launch_bounds__(256) void scatter_kernel(const void* __restrict__ edges,
                                                      const int* __restrict__ mode,
                                                      const int* __restrict__ moff,
                                                      int* __restrict__ pairs,
                                                      int E, int nb, int chunk) {
  __shared__ int cur[1024];
  int m = mode[0];
  for (int j = threadIdx.x; j < nb; j += 256)
    cur[j] = moff[(size_t)j * NCHUNK + blockIdx.x];
  __syncthreads();
  long long lo = (long long)blockIdx.x * chunk;
  long long hi = lo + chunk;
  if (hi > E) hi = E;
  for (long long i = lo + threadIdx.x; i < hi; i += 256) {
    int r = edge_at(edges, i, m);
    int c = edge_at(edges, (long long)E + i, m);
    int pos = atomicAdd(&cur[c >> 8], 1);
    pairs[pos] = (r << 8) | (c & 255);
  }
}

__global__ __launch_bounds__(256) void passB1_kernel(const int* __restrict__ pairs,
                                                     const int* __restrict__ moff,
                                                     int* __restrict__ deg, int n) {
  __shared__ int h[256];
  int b = blockIdx.x;
  h[threadIdx.x] = 0;
  __syncthreads();
  int lo = moff[(size_t)b * NCHUNK];
  int hi = moff[(size_t)(b + 1) * NCHUNK];
  for (int e = lo + threadIdx.x; e < hi; e += 256)
    atomicAdd(&h[pairs[e] & 255], 1);
  __syncthreads();
  int node = b * 256 + threadIdx.x;
  if (node < n) deg[node] = h[threadIdx.x];
}

__global__ void dinv_kernel(const int* __restrict__ deg, float* __restrict__ dinv, int n) {
  int i = blockIdx.x * blockDim.x + threadIdx.x;
  if (i < n) dinv[i] = deg[i] > 0 ? rsqrtf((float)deg[i]) : 0.f;
}

__global__ __launch_bounds__(256) void passB2_kernel(const int* __restrict__ pairs,
                                                     const int* __restrict__ moff,
                                                     const int* __restrict__ offsets,
                                                     int* __restrict__ csr_row, int n) {
  __shared__ int cur[256];
  int b = blockIdx.x;
  int node = b * 256 + threadIdx.x;
  cur[threadIdx.x] = (node < n) ? offsets[node] : 0;
  __syncthreads();
  int lo = moff[(size_t)b * NCHUNK];
  int hi = moff[(size_t)(b + 1) * NCHUNK];
  for (int e = lo + threadIdx.x; e < hi; e += 256) {
    int p = pairs[e];
    int pos = atomicAdd(&cur[p & 255], 1);
    csr_row[pos] = p >> 8;
  }
}

// ---------------- per-layer prep: fold BN affine into W ----------------
// Wt[nc][k] = bf16( (use_scale ? scale[k] : 1) * W[k][nc] )
__global__ __launch_bounds__(256) void prepW_kernel(const float* __restrict__ W,
                                                    const float* __restrict__ scale,
                                                    int use_scale,
                                                    unsigned short* __restrict__ Wt) {
  int idx = blockIdx.x * 256 + threadIdx.x;  // 64 blocks * 256 = 16384
  int nc = idx >> 7, k = idx & 127;
  float v = W[(size_t)k * 128 + nc];
  if (use_scale) v *= scale[k];
  Wt[(size_t)nc * 128 + k] = f2bf(v);
}

// rbias[nc] = sum_k shift[k] * W[k][nc]  (0 for layer 0)
__global__ void prepR_kernel(const float* __restrict__ W, const float* __restrict__ shift,
                             int use_shift, float* __restrict__ rbias) {
  int nc = threadIdx.x;
  float s = 0.f;
  if (use_shift) {
    for (int k = 0; k < 128; k++) s += shift[k] * W[(size_t)k * 128 + nc];
  }
  rbias[nc] = s;
}

// ---------------- MFMA GEMM: xb = bf16( dinv * (A @ W' + r) ) ----------------
// No LDS: A rows are block-private (read once), W't (32 KB) is L1/L2-resident.
// Frag layouts (16x16x32 bf16): A lane l: A[m=l&15][k=(l>>4)*8+j] (8 contig);
// B lane l: B[k=(l>>4)*8+j][n=l&15] = Wt[n][k] (8 contig); D: col=l&15, row=(l>>4)*4+r.
template <int A_IS_FP32>
__global__ __launch_bounds__(256) void gemm_mfma_kernel(
    const void* __restrict__ Ain, const unsigned short* __restrict__ Wt,
    const float* __restrict__ rbias, const float* __restrict__ dinv,
    unsigned short* __restrict__ xb, int n) {
  int l = threadIdx.x & 63;
  int w = threadIdx.x >> 6;
  int row0 = blockIdx.x * 64 + w * 16;
  int am = row0 + (l & 15);
  int amc = am < n ? am : n - 1;  // clamp: OOB rows computed but never stored
  int kg = l >> 4;                // k-group

  f32x4 acc[8];
#pragma unroll
  for (int nt = 0; nt < 8; nt++) {
    f32x4 zv = {0.f, 0.f, 0.f, 0.f};
    acc[nt] = zv;
  }

#pragma unroll
  for (int kk = 0; kk < 4; kk++) {
    bf16x8 a;
    if (A_IS_FP32) {
      const float* ap = (const float*)Ain + (size_t)amc * 128 + kk * 32 + kg * 8;
      float4 f0 = *(const float4*)ap;
      float4 f1 = *(const float4*)(ap + 4);
      a[0] = (short)f2bf(f0.x); a[1] = (short)f2bf(f0.y);
      a[2] = (short)f2bf(f0.z); a[3] = (short)f2bf(f0.w);
      a[4] = (short)f2bf(f1.x); a[5] = (short)f2bf(f1.y);
      a[6] = (short)f2bf(f1.z); a[7] = (short)f2bf(f1.w);
    } else {
      a = *(const bf16x8*)((const unsigned short*)Ain + (size_t)amc * 128 + kk * 32 + kg * 8);
    }
#pragma unroll
    for (int nt = 0; nt < 8; nt++) {
      bf16x8 b = *(const bf16x8*)(Wt + (size_t)(nt * 16 + (l & 15)) * 128 + kk * 32 + kg * 8);
      acc[nt] = __builtin_amdgcn_mfma_f32_16x16x32_bf16(a, b, acc[nt], 0, 0, 0);
    }
  }

  int col0 = l & 15;
  int rbase = row0 + (l >> 4) * 4;
  float dv[4];
#pragma unroll
  for (int r = 0; r < 4; r++) {
    int rr = rbase + r;
    dv[r] = dinv[rr < n ? rr : n - 1];
  }
#pragma unroll
  for (int nt = 0; nt < 8; nt++) {
    float rb = rbias[nt * 16 + col0];
#pragma unroll
    for (int r = 0; r < 4; r++) {
      int rr = rbase + r;
      if (rr < n)
        xb[(size_t)rr * 128 + nt * 16 + col0] = f2bf((acc[nt][r] + rb) * dv[r]);
    }
  }
}

// ---------------- aggregation: z[c] = dinv[c] * sum_in xb[row] ----------------
// 16 lanes per node (uint4 = 8 bf16 each), unroll-by-4 independent accumulators.
template <int F32OUT>
__global__ __launch_bounds__(256) void agg_kernel(
    const uint4* __restrict__ x4, const int* __restrict__ csr_row,
    const int* __restrict__ offsets, const float* __restrict__ dinv,
    void* __restrict__ z, int n) {
  int node = blockIdx.x * 16 + (threadIdx.x >> 4);
  int d8 = threadIdx.x & 15;  // 8 bf16 per lane
  if (node >= n) return;
  int lo = offsets[node], hi = offsets[node + 1];
  float a0[8] = {}, a1[8] = {}, a2[8] = {}, a3[8] = {};
#define ACC8(A, v)                                                         \
  A[0] += __uint_as_float((v).x << 16); A[1] += __uint_as_float((v).x & 0xffff0000u); \
  A[2] += __uint_as_float((v).y << 16); A[3] += __uint_as_float((v).y & 0xffff0000u); \
  A[4] += __uint_as_float((v).z << 16); A[5] += __uint_as_float((v).z & 0xffff0000u); \
  A[6] += __uint_as_float((v).w << 16); A[7] += __uint_as_float((v).w & 0xffff0000u);
  int e = lo;
  for (; e + 4 <= hi; e += 4) {
    int r0 = csr_row[e];
    int r1 = csr_row[e + 1];
    int r2 = csr_row[e + 2];
    int r3 = csr_row[e + 3];
    uint4 v0 = x4[(size_t)r0 * 16 + d8];
    uint4 v1 = x4[(size_t)r1 * 16 + d8];
    uint4 v2 = x4[(size_t)r2 * 16 + d8];
    uint4 v3 = x4[(size_t)r3 * 16 + d8];
    ACC8(a0, v0) ACC8(a1, v1) ACC8(a2, v2) ACC8(a3, v3)
  }
  for (; e < hi; e++) {
    uint4 v = x4[(size_t)csr_row[e] * 16 + d8];
    ACC8(a0, v)
  }
#undef ACC8
  float dvn = dinv[node];
  float s[8];
#pragma unroll
  for (int j = 0; j < 8; j++) s[j] = (a0[j] + a1[j] + a2[j] + a3[j]) * dvn;
  if (F32OUT) {
    float* zp = (float*)z + (size_t)node * 128 + d8 * 8;
    *(float4*)zp = make_float4(s[0], s[1], s[2], s[3]);
    *(float4*)(zp + 4) = make_float4(s[4], s[5], s[6], s[7]);
  } else {
    uint4 o = make_uint4(pack2bf(s[0], s[1]), pack2bf(s[2], s[3]),
                         pack2bf(s[4], s[5]), pack2bf(s[6], s[7]));
    *(uint4*)((unsigned short*)z + (size_t)node * 128 + d8 * 8) = o;
  }
}

// ---------------- BN stats / finalize / final norm ----------------
template <int F32IN>
__global__ __launch_bounds__(128) void stats_kernel(
    const void* __restrict__ z, float* __restrict__ colsum,
    float* __restrict__ colsumsq, int n) {
  int d = threadIdx.x;
  float s = 0.f, s2 = 0.f;
  for (int r = blockIdx.x; r < n; r += gridDim.x) {
    float v;
    if (F32IN) v = ((const float*)z)[(size_t)r * 128 + d];
    else v = __uint_as_float((unsigned int)((const unsigned short*)z)[(size_t)r * 128 + d] << 16);
    s += v;
    s2 += v * v;
  }
  atomicAdd(&colsum[d], s);
  atomicAdd(&colsumsq[d], s2);
}

__global__ void finalize_kernel(const float* __restrict__ colsum,
                                const float* __restrict__ colsumsq,
                                const float* __restrict__ gamma,
                                const float* __restrict__ beta,
                                float* __restrict__ scale, float* __restrict__ shift,
                                float invN) {
  int d = threadIdx.x;
  float mu = colsum[d] * invN;
  float var = colsumsq[d] * invN - mu * mu;
  var = fmaxf(var, 0.f);
  float sc = gamma[d] * rsqrtf(var + BN_EPS);
  scale[d] = sc;
  shift[d] = beta[d] - mu * sc;
}

// in-place fp32 affine on d_out (layer 2)
__global__ __launch_bounds__(256) void norm_kernel(
    float* __restrict__ z, const float* __restrict__ scale,
    const float* __restrict__ shift, int total4) {
  int idx = blockIdx.x * blockDim.x + threadIdx.x;
  int stride = gridDim.x * blockDim.x;
  for (int i = idx; i < total4; i += stride) {
    float4 v = ((const float4*)z)[i];
    int d0 = (i & 31) * 4;
    v.x = v.x * scale[d0] + shift[d0];
    v.y = v.y * scale[d0 + 1] + shift[d0 + 1];
    v.z = v.z * scale[d0 + 2] + shift[d0 + 2];
    v.w = v.w * scale[d0 + 3] + shift[d0 + 3];
    ((float4*)z)[i] = v;
  }
}

// ---------------- launcher ----------------

extern "C" void kernel_launch(void* const* d_in, const int* in_sizes, int n_in,
                              void* d_out, int out_size, void* d_ws, size_t ws_size,
                              hipStream_t stream) {
  const float* feats = (const float*)d_in[0];
  const void* edges = d_in[1];
  const float* W = (const float*)d_in[2];
  const float* gamma = (const float*)d_in[4];
  const float* beta = (const float*)d_in[5];

  const int n = in_sizes[0] / 128;
  const int E = in_sizes[1] / 2;

  const int nb = (n + 255) / 256;
  const int m = nb * NCHUNK;
  const int chunk = (E + NCHUNK - 1) / NCHUNK;
  const int sb_n = (n + 1023) / 1024;
  const int sb_m = (m + 1023) / 1024;
  const int sb_max = sb_n > sb_m ? sb_n : sb_m;

  char* ws = (char*)d_ws;
  size_t off = 0;
  unsigned short* xb = (unsigned short*)(ws + off); off += (size_t)n * 128 * 2; off = (off + 255) & ~(size_t)255;
  int* deg = (int*)(ws + off); off += (size_t)n * 4;
  float* dinv = (float*)(ws + off); off += (size_t)n * 4;
  int* offsets = (int*)(ws + off); off += (size_t)(n + 1) * 4; off = (off + 255) & ~(size_t)255;
  int* csr_row = (int*)(ws + off); off += (size_t)E * 4; off = (off + 255) & ~(size_t)255;
  int* pairs = (int*)(ws + off); off += (size_t)E * 4; off = (off + 255) & ~(size_t)255;
  int* blockcounts = (int*)(ws + off); off += (size_t)m * 4; off = (off + 255) & ~(size_t)255;
  int* moff = (int*)(ws + off); off += (size_t)(m + 1) * 4; off = (off + 255) & ~(size_t)255;
  int* tprefix = (int*)(ws + off); off += (size_t)sb_max * 256 * 4; off = (off + 255) & ~(size_t)255;
  int* bsum = (int*)(ws + off); off += 256 * 4;
  unsigned short* Wt = (unsigned short*)(ws + off); off += 128 * 128 * 2; off = (off + 255) & ~(size_t)255;
  float* rbias = (float*)(ws + off); off += 128 * 4;
  float* colsum = (float*)(ws + off); off += 128 * 4;
  float* colsumsq = (float*)(ws + off); off += 128 * 4;
  float* scale = (float*)(ws + off); off += 128 * 4;
  float* shift = (float*)(ws + off); off += 128 * 4;
  int* mode = (int*)(ws + off); off += 4;

  // ---- contention-free CSR build (graph is layer-invariant) ----
  detect_kernel<<<1, 1, 0, stream>>>((const int*)edges, mode);
  count_kernel<<<NCHUNK, 256, 0, stream>>>(edges, mode, blockcounts, E, nb, chunk);
  scan1_kernel<<<sb_m, 256, 0, stream>>>(blockcounts, tprefix, bsum, m);
  scan2_kernel<<<1, 256, 0, stream>>>(bsum, sb_m, moff, m);
  scan3_kernel<<<sb_m, 256, 0, stream>>>(blockcounts, tprefix, bsum, moff, m);
  scatter_kernel<<<NCHUNK, 256, 0, stream>>>(edges, mode, moff, pairs, E, nb, chunk);
  passB1_kernel<<<nb, 256, 0, stream>>>(pairs, moff, deg, n);
  dinv_kernel<<<(n + 255) / 256, 256, 0, stream>>>(deg, dinv, n);
  scan1_kernel<<<sb_n, 256, 0, stream>>>(deg, tprefix, bsum, n);
  scan2_kernel<<<1, 256, 0, stream>>>(bsum, sb_n, offsets, n);
  scan3_kernel<<<sb_n, 256, 0, stream>>>(deg, tprefix, bsum, offsets, n);
  passB2_kernel<<<nb, 256, 0, stream>>>(pairs, moff, offsets, csr_row, n);

  unsigned short* zb = (unsigned short*)d_out;  // bf16 z for layers 0,1 (first half of d_out)
  float* zf = (float*)d_out;                    // fp32 z for layer 2 (full d_out)
  const int ggrid = (n + 63) / 64;

  for (int l = 0; l < 3; l++) {
    prepW_kernel<<<64, 256, 0, stream>>>(W + (size_t)l * 16384, scale, l > 0 ? 1 : 0, Wt);
    prepR_kernel<<<1, 128, 0, stream>>>(W + (size_t)l * 16384, shift, l > 0 ? 1 : 0, rbias);
    if (l == 0)
      gemm_mfma_kernel<1><<<ggrid, 256, 0, stream>>>(feats, Wt, rbias, dinv, xb, n);
    else
      gemm_mfma_kernel<0><<<ggrid, 256, 0, stream>>>(zb, Wt, rbias, dinv, xb, n);
    hipMemsetAsync(colsum, 0, 2 * 128 * 4, stream);  // colsum+colsumsq contiguous
    if (l < 2) {
      agg_kernel<0><<<(n + 15) / 16, 256, 0, stream>>>(
          (const uint4*)xb, csr_row, offsets, dinv, zb, n);
      stats_kernel<0><<<512, 128, 0, stream>>>(zb, colsum, colsumsq, n);
    } else {
      agg_kernel<1><<<(n + 15) / 16, 256, 0, stream>>>(
          (const uint4*)xb, csr_row, offsets, dinv, zf, n);
      stats_kernel<1><<<512, 128, 0, stream>>>(zf, colsum, colsumsq, n);
    }
    finalize_kernel<<<1, 128, 0, stream>>>(colsum, colsumsq, gamma + l * 128,
                                           beta + l * 128, scale, shift, 1.0f / (float)n);
  }
  norm_kernel<<<2048, 256, 0, stream>>>(zf, scale, shift, (n * 128) / 4);
}